// Round 1
// baseline (14233.246 us; speedup 1.0000x reference)
//
#include <hip/hip_runtime.h>
#include <math.h>

#define NTOK 4096      // B*N = 4*1024
#define SEQ  1024
#define DIMM 1024
#define EPSV 1e-5f

__device__ inline float wave_sum(float v) {
    #pragma unroll
    for (int off = 32; off > 0; off >>= 1) v += __shfl_xor(v, off, 64);
    return v;
}
__device__ inline float wave_max(float v) {
    #pragma unroll
    for (int off = 32; off > 0; off >>= 1) v = fmaxf(v, __shfl_xor(v, off, 64));
    return v;
}

// ---------------- LayerNorm (biased var, gain only, optional residual add) ----
// out[r,:] = (in[r,:]-mean)*rsqrt(var+eps)*g  (+ res[r,:] if res != null)
// D = NV*1024, 256 threads/block, one block per row.
template <int NV>
__global__ __launch_bounds__(256) void ln_kernel(
    const float* __restrict__ in, int in_ld,
    float* __restrict__ out, int out_ld,
    const float* __restrict__ g,
    const float* __restrict__ res) {
    const int D = NV * 1024;
    int r = blockIdx.x;
    const float* row = in + (size_t)r * in_ld;
    float4 vals[NV];
    float s = 0.f, sq = 0.f;
    #pragma unroll
    for (int i = 0; i < NV; ++i) {
        int c = (i * 256 + threadIdx.x) * 4;
        float4 v = *(const float4*)(row + c);
        vals[i] = v;
        s += v.x + v.y + v.z + v.w;
        sq += v.x * v.x + v.y * v.y + v.z * v.z + v.w * v.w;
    }
    s = wave_sum(s); sq = wave_sum(sq);
    __shared__ float red[2][4];
    int w = threadIdx.x >> 6, lane = threadIdx.x & 63;
    if (lane == 0) { red[0][w] = s; red[1][w] = sq; }
    __syncthreads();
    s  = red[0][0] + red[0][1] + red[0][2] + red[0][3];
    sq = red[1][0] + red[1][1] + red[1][2] + red[1][3];
    float mean = s / D;
    float var = sq / D - mean * mean;
    float rs = rsqrtf(var + EPSV);
    float* orow = out + (size_t)r * out_ld;
    const float* rrow = res ? (res + (size_t)r * out_ld) : nullptr;
    #pragma unroll
    for (int i = 0; i < NV; ++i) {
        int c = (i * 256 + threadIdx.x) * 4;
        float4 v = vals[i];
        float4 gv = *(const float4*)(g + c);
        float4 o;
        o.x = (v.x - mean) * rs * gv.x;
        o.y = (v.y - mean) * rs * gv.y;
        o.z = (v.z - mean) * rs * gv.z;
        o.w = (v.w - mean) * rs * gv.w;
        if (rrow) {
            float4 rv = *(const float4*)(rrow + c);
            o.x += rv.x; o.y += rv.y; o.z += rv.z; o.w += rv.w;
        }
        *(float4*)(orow + c) = o;
    }
}

// ---------------- fp32 tiled GEMM: C[M,N] = A[M,K] @ B[K,N] ------------------
// 64x64 tile, BK=16, 256 threads, 4x4 micro-tile per thread.
#define BM 64
#define BN 64
#define BK 16
__global__ __launch_bounds__(256) void gemm_kernel(
    const float* __restrict__ A, int lda,
    const float* __restrict__ B, int ldb,
    float* __restrict__ C, int ldc, int K) {
    __shared__ float As[BK][BM + 4];
    __shared__ float Bs[BK][BN + 4];
    int bm = blockIdx.x * BM;
    int bn = blockIdx.y * BN;
    int tid = threadIdx.x;
    int tm = (tid >> 4) * 4;
    int tn = (tid & 15) * 4;
    // staging map
    int arow = tid >> 2, ak = (tid & 3) * 4;   // A: 64 rows x 16 k
    int bk = tid >> 4, bn0 = (tid & 15) * 4;   // B: 16 k x 64 n
    const float* Ap = A + (size_t)(bm + arow) * lda + ak;
    const float* Bp = B + (size_t)bk * ldb + bn + bn0;
    float acc[4][4] = {};
    for (int k0 = 0; k0 < K; k0 += BK) {
        float4 av = *(const float4*)Ap;
        float4 bv = *(const float4*)Bp;
        Ap += BK;
        Bp += (size_t)BK * ldb;
        __syncthreads();
        As[ak + 0][arow] = av.x;
        As[ak + 1][arow] = av.y;
        As[ak + 2][arow] = av.z;
        As[ak + 3][arow] = av.w;
        *(float4*)&Bs[bk][bn0] = bv;
        __syncthreads();
        #pragma unroll
        for (int kk = 0; kk < BK; ++kk) {
            float4 a = *(const float4*)&As[kk][tm];
            float4 b = *(const float4*)&Bs[kk][tn];
            float av4[4] = {a.x, a.y, a.z, a.w};
            float bv4[4] = {b.x, b.y, b.z, b.w};
            #pragma unroll
            for (int i = 0; i < 4; ++i)
                #pragma unroll
                for (int j = 0; j < 4; ++j)
                    acc[i][j] = fmaf(av4[i], bv4[j], acc[i][j]);
        }
    }
    #pragma unroll
    for (int i = 0; i < 4; ++i) {
        float4 o = make_float4(acc[i][0], acc[i][1], acc[i][2], acc[i][3]);
        *(float4*)(C + (size_t)(bm + tm + i) * ldc + bn + tn) = o;
    }
}

// ---------------- fused causal attention (online softmax, fp32) --------------
// qkv: [4096, 3072] token-major (q|k|v each [.,1024] with col h*64+d)
// O:   [4096, 1024]
__global__ __launch_bounds__(256) void attn_kernel(
    const float* __restrict__ qkv, float* __restrict__ O) {
    int bh = blockIdx.x;           // 0..63
    int b = bh >> 4, h = bh & 15;
    int i0 = blockIdx.y * 4;
    int w = threadIdx.x >> 6, lane = threadIdx.x & 63;
    int i = i0 + w;                // this wave's query row
    __shared__ float kt[64][68];
    __shared__ float vt[64][68];
    __shared__ float qs[4][64];
    __shared__ float ps[4][64];
    size_t base = ((size_t)b * SEQ) * 3072 + (size_t)h * 64;
    float qv = qkv[base + (size_t)i * 3072 + lane] * 0.125f;  // 64^-0.5
    qs[w][lane] = qv;
    float m = -INFINITY, l = 0.f, o = 0.f;
    int ntiles = (i0 + 3) / 64 + 1;
    for (int jt = 0; jt < ntiles; ++jt) {
        __syncthreads();
        // stage 64 K rows + 64 V rows (float4 coalesced)
        for (int t = threadIdx.x; t < 1024; t += 256) {
            int jr = t >> 4;
            int c = (t & 15) * 4;
            size_t gg = base + (size_t)(jt * 64 + jr) * 3072 + c;
            *(float4*)&kt[jr][c] = *(const float4*)(qkv + gg + 1024);
            *(float4*)&vt[jr][c] = *(const float4*)(qkv + gg + 2048);
        }
        __syncthreads();
        if ((i >> 6) >= jt) {
            int j = jt * 64 + lane;
            float s = 0.f;
            #pragma unroll
            for (int dd = 0; dd < 16; ++dd) {
                float4 q4 = *(const float4*)&qs[w][dd * 4];
                float4 k4 = *(const float4*)&kt[lane][dd * 4];
                s = fmaf(q4.x, k4.x, s);
                s = fmaf(q4.y, k4.y, s);
                s = fmaf(q4.z, k4.z, s);
                s = fmaf(q4.w, k4.w, s);
            }
            bool valid = (j <= i);
            s = valid ? s : -INFINITY;
            float tmax = wave_max(s);
            float mnew = fmaxf(m, tmax);
            float p = valid ? __expf(s - mnew) : 0.f;
            float corr = __expf(m - mnew);     // 0 on first tile (m = -inf)
            float psum = wave_sum(p);
            l = l * corr + psum;
            m = mnew;
            ps[w][lane] = p;
            o *= corr;
            #pragma unroll
            for (int j4 = 0; j4 < 16; ++j4) {
                float4 p4 = *(const float4*)&ps[w][j4 * 4];
                o = fmaf(p4.x, vt[j4 * 4 + 0][lane], o);
                o = fmaf(p4.y, vt[j4 * 4 + 1][lane], o);
                o = fmaf(p4.z, vt[j4 * 4 + 2][lane], o);
                o = fmaf(p4.w, vt[j4 * 4 + 3][lane], o);
            }
        }
    }
    O[((size_t)b * SEQ + i) * 1024 + h * 64 + lane] = o / l;
}

// ---------------- GEGLU: hh[r,c] = a * gelu_exact(gate), in-place ------------
__global__ __launch_bounds__(256) void geglu_kernel(float* __restrict__ hh) {
    size_t idx = (size_t)blockIdx.x * 256 + threadIdx.x;  // over 4096*1024 float4s
    size_t r = idx >> 10;
    int c = (int)(idx & 1023) * 4;
    float* arow = hh + r * 8192;
    float4 a = *(const float4*)(arow + c);
    float4 g = *(const float4*)(arow + 4096 + c);
    float4 o;
    o.x = a.x * 0.5f * g.x * (1.f + erff(g.x * 0.70710678118654752f));
    o.y = a.y * 0.5f * g.y * (1.f + erff(g.y * 0.70710678118654752f));
    o.z = a.z * 0.5f * g.z * (1.f + erff(g.z * 0.70710678118654752f));
    o.w = a.w * 0.5f * g.w * (1.f + erff(g.w * 0.70710678118654752f));
    *(float4*)(arow + c) = o;
}

// ---------------- residual add: X += C ---------------------------------------
__global__ __launch_bounds__(256) void add_kernel(
    float* __restrict__ X, const float* __restrict__ Cc) {
    size_t idx = ((size_t)blockIdx.x * 256 + threadIdx.x) * 4;
    float4 x = *(const float4*)(X + idx);
    float4 c = *(const float4*)(Cc + idx);
    x.x += c.x; x.y += c.y; x.z += c.z; x.w += c.w;
    *(float4*)(X + idx) = x;
}

extern "C" void kernel_launch(void* const* d_in, const int* in_sizes, int n_in,
                              void* d_out, int out_size, void* d_ws, size_t ws_size,
                              hipStream_t stream) {
    const float* x_in    = (const float*)d_in[0];
    const float* qkv_w   = (const float*)d_in[1];
    const float* out_w   = (const float*)d_in[2];
    const float* ff_w1   = (const float*)d_in[3];
    const float* ff_w2   = (const float*)d_in[4];
    const float* attn_g  = (const float*)d_in[5];
    const float* outln_g = (const float*)d_in[6];
    const float* ffn_g   = (const float*)d_in[7];
    const float* ffln_g  = (const float*)d_in[8];
    const float* nin_g   = (const float*)d_in[9];
    const float* nout_g  = (const float*)d_in[10];
    float* out = (float*)d_out;

    float* X   = (float*)d_ws;            // [4096,1024]
    float* A   = X + (size_t)NTOK * DIMM; // [4096,1024]
    float* C   = A + (size_t)NTOK * DIMM; // [4096,1024]
    float* BIG = C + (size_t)NTOK * DIMM; // [4096,8192]

    dim3 blk(256);
    // x = LN(x, norm_in_g)
    ln_kernel<1><<<NTOK, blk, 0, stream>>>(x_in, 1024, X, 1024, nin_g, nullptr);

    for (int l = 0; l < 6; ++l) {
        // attention block
        ln_kernel<1><<<NTOK, blk, 0, stream>>>(X, 1024, A, 1024, attn_g + l * 1024, nullptr);
        gemm_kernel<<<dim3(64, 48), blk, 0, stream>>>(A, 1024, qkv_w + (size_t)l * 1024 * 3072, 3072, BIG, 3072, 1024);
        attn_kernel<<<dim3(64, 256), blk, 0, stream>>>(BIG, C);
        gemm_kernel<<<dim3(64, 16), blk, 0, stream>>>(C, 1024, out_w + (size_t)l * 1024 * 1024, 1024, A, 1024, 1024);
        // X = LN(proj)*g + X
        ln_kernel<1><<<NTOK, blk, 0, stream>>>(A, 1024, X, 1024, outln_g + l * 1024, X);
        // feedforward block
        ln_kernel<1><<<NTOK, blk, 0, stream>>>(X, 1024, A, 1024, ffn_g + l * 1024, nullptr);
        gemm_kernel<<<dim3(64, 128), blk, 0, stream>>>(A, 1024, ff_w1 + (size_t)l * 1024 * 8192, 8192, BIG, 8192, 1024);
        geglu_kernel<<<16384, blk, 0, stream>>>(BIG);
        ln_kernel<4><<<NTOK, blk, 0, stream>>>(BIG, 8192, BIG, 8192, ffln_g + l * 4096, nullptr);
        gemm_kernel<<<dim3(64, 16), blk, 0, stream>>>(BIG, 8192, ff_w2 + (size_t)l * 4096 * 1024, 1024, C, 1024, 4096);
        add_kernel<<<4096, blk, 0, stream>>>(X, C);
    }
    ln_kernel<1><<<NTOK, blk, 0, stream>>>(X, 1024, out, 1024, nout_g, nullptr);
}

// Round 2
// 6821.407 us; speedup vs baseline: 2.0866x; 2.0866x over previous
//
#include <hip/hip_runtime.h>
#include <math.h>

#define NTOK 4096      // B*N = 4*1024
#define SEQ  1024
#define EPSV 1e-5f

#define AS1 __attribute__((address_space(1)))
#define AS3 __attribute__((address_space(3)))

typedef __attribute__((ext_vector_type(8))) short short8;
typedef __attribute__((ext_vector_type(4))) float f32x4;

__device__ inline float wave_sum(float v) {
    #pragma unroll
    for (int off = 32; off > 0; off >>= 1) v += __shfl_xor(v, off, 64);
    return v;
}
__device__ inline float wave_max(float v) {
    #pragma unroll
    for (int off = 32; off > 0; off >>= 1) v = fmaxf(v, __shfl_xor(v, off, 64));
    return v;
}

// ---- bf16 split helpers (hi = RNE bf16, lo = RNE bf16 of residual) ----------
__device__ inline ushort f2bf(float x) {
    unsigned u = __builtin_bit_cast(unsigned, x);
    u += 0x7fff + ((u >> 16) & 1);
    return (ushort)(u >> 16);
}
__device__ inline float bf2f(ushort h) {
    unsigned u = ((unsigned)h) << 16;
    return __builtin_bit_cast(float, u);
}
__device__ inline void split2(float x, ushort& h, ushort& l) {
    h = f2bf(x);
    l = f2bf(x - bf2f(h));
}

// ---------------- LayerNorm fp32-out (optional residual add) -----------------
template <int NV>
__global__ __launch_bounds__(256) void ln_kernel(
    const float* __restrict__ in, int in_ld,
    float* __restrict__ out, int out_ld,
    const float* __restrict__ g,
    const float* __restrict__ res) {
    const int D = NV * 1024;
    int r = blockIdx.x;
    const float* row = in + (size_t)r * in_ld;
    float4 vals[NV];
    float s = 0.f, sq = 0.f;
    #pragma unroll
    for (int i = 0; i < NV; ++i) {
        int c = (i * 256 + threadIdx.x) * 4;
        float4 v = *(const float4*)(row + c);
        vals[i] = v;
        s += v.x + v.y + v.z + v.w;
        sq += v.x * v.x + v.y * v.y + v.z * v.z + v.w * v.w;
    }
    s = wave_sum(s); sq = wave_sum(sq);
    __shared__ float red[2][4];
    int w = threadIdx.x >> 6, lane = threadIdx.x & 63;
    if (lane == 0) { red[0][w] = s; red[1][w] = sq; }
    __syncthreads();
    s  = red[0][0] + red[0][1] + red[0][2] + red[0][3];
    sq = red[1][0] + red[1][1] + red[1][2] + red[1][3];
    float mean = s / D;
    float var = sq / D - mean * mean;
    float rs = rsqrtf(var + EPSV);
    float* orow = out + (size_t)r * out_ld;
    const float* rrow = res ? (res + (size_t)r * out_ld) : nullptr;
    #pragma unroll
    for (int i = 0; i < NV; ++i) {
        int c = (i * 256 + threadIdx.x) * 4;
        float4 v = vals[i];
        float4 gv = *(const float4*)(g + c);
        float4 o;
        o.x = (v.x - mean) * rs * gv.x;
        o.y = (v.y - mean) * rs * gv.y;
        o.z = (v.z - mean) * rs * gv.z;
        o.w = (v.w - mean) * rs * gv.w;
        if (rrow) {
            float4 rv = *(const float4*)(rrow + c);
            o.x += rv.x; o.y += rv.y; o.z += rv.z; o.w += rv.w;
        }
        *(float4*)(orow + c) = o;
    }
}

// ---------------- LayerNorm with fused bf16 hi/lo split output ---------------
template <int NV>
__global__ __launch_bounds__(256) void ln_split_kernel(
    const float* __restrict__ in, int in_ld,
    ushort* __restrict__ hi, ushort* __restrict__ lo,
    const float* __restrict__ g) {
    const int D = NV * 1024;
    int r = blockIdx.x;
    const float* row = in + (size_t)r * in_ld;
    float4 vals[NV];
    float s = 0.f, sq = 0.f;
    #pragma unroll
    for (int i = 0; i < NV; ++i) {
        int c = (i * 256 + threadIdx.x) * 4;
        float4 v = *(const float4*)(row + c);
        vals[i] = v;
        s += v.x + v.y + v.z + v.w;
        sq += v.x * v.x + v.y * v.y + v.z * v.z + v.w * v.w;
    }
    s = wave_sum(s); sq = wave_sum(sq);
    __shared__ float red[2][4];
    int w = threadIdx.x >> 6, lane = threadIdx.x & 63;
    if (lane == 0) { red[0][w] = s; red[1][w] = sq; }
    __syncthreads();
    s  = red[0][0] + red[0][1] + red[0][2] + red[0][3];
    sq = red[1][0] + red[1][1] + red[1][2] + red[1][3];
    float mean = s / D;
    float var = sq / D - mean * mean;
    float rs = rsqrtf(var + EPSV);
    #pragma unroll
    for (int i = 0; i < NV; ++i) {
        int c = (i * 256 + threadIdx.x) * 4;
        float4 v = vals[i];
        float4 gv = *(const float4*)(g + c);
        float o0 = (v.x - mean) * rs * gv.x;
        float o1 = (v.y - mean) * rs * gv.y;
        float o2 = (v.z - mean) * rs * gv.z;
        float o3 = (v.w - mean) * rs * gv.w;
        ushort4 h, lw;
        split2(o0, h.x, lw.x); split2(o1, h.y, lw.y);
        split2(o2, h.z, lw.z); split2(o3, h.w, lw.w);
        *(ushort4*)(hi + (size_t)r * D + c) = h;
        *(ushort4*)(lo + (size_t)r * D + c) = lw;
    }
}

// ---------------- weight transpose + split: in[K][N] f32 -> out[N][K] bf16 ---
__global__ __launch_bounds__(256) void tsplit_kernel(
    const float* __restrict__ in, ushort* __restrict__ hi, ushort* __restrict__ lo,
    int K, int N) {
    __shared__ float t[32][33];
    int n0 = blockIdx.x * 32, k0 = blockIdx.y * 32;
    int tr = threadIdx.x >> 3, tc = (threadIdx.x & 7) * 4;
    float4 v = *(const float4*)(in + (size_t)(k0 + tr) * N + n0 + tc);
    t[tr][tc + 0] = v.x; t[tr][tc + 1] = v.y; t[tr][tc + 2] = v.z; t[tr][tc + 3] = v.w;
    __syncthreads();
    float a0 = t[tc + 0][tr], a1 = t[tc + 1][tr], a2 = t[tc + 2][tr], a3 = t[tc + 3][tr];
    ushort4 h, lw;
    split2(a0, h.x, lw.x); split2(a1, h.y, lw.y);
    split2(a2, h.z, lw.z); split2(a3, h.w, lw.w);
    size_t o = (size_t)(n0 + tr) * K + k0 + tc;
    *(ushort4*)(hi + o) = h;
    *(ushort4*)(lo + o) = lw;
}

// ---------------- split-bf16 MFMA GEMM: C[M,N] = (Ahi+Alo)(Bhi+Blo) ----------
// A*: [M][K] bf16 row-major; B*: [N][K] bf16 row-major (i.e. B^T); C fp32.
// 128x128 tile, BK=32, 256 threads (4 waves, 2x2), 16x16x32 MFMA, 3 products.
__global__ __launch_bounds__(256) void mgemm_kernel(
    const ushort* __restrict__ Ahi, const ushort* __restrict__ Alo,
    const ushort* __restrict__ Bhi, const ushort* __restrict__ Blo,
    float* __restrict__ C, int ldc, int K) {
    __shared__ ushort lds[16384];   // 4 buffers (Ahi,Alo,Bhi,Blo) x 128x32 bf16 = 32 KB
    const int tid = threadIdx.x;
    const int w = tid >> 6, l = tid & 63;
    const int wr = w >> 1, wc = w & 1;
    const int rl = l & 15, kc = l >> 4;
    const int bm = blockIdx.x * 128, bn = blockIdx.y * 128;

    // staging source offsets (inverse-XOR-swizzled k-chunk so linear LDS write
    // + swizzled LDS read cancel; rule: both-sides-or-neither)
    size_t gA[2], gB[2];
    #pragma unroll
    for (int c = 0; c < 2; ++c) {
        int r = c * 64 + (tid >> 2);
        int slot = tid & 3;
        int ko = 8 * (slot ^ ((r >> 1) & 3));
        gA[c] = (size_t)(bm + r) * K + ko;
        gB[c] = (size_t)(bn + r) * K + ko;
    }
    // fragment read byte offsets (swizzled)
    int aoff[4], boff[4];
    #pragma unroll
    for (int m = 0; m < 4; ++m) {
        int ra = wr * 64 + m * 16 + rl;
        aoff[m] = ra * 64 + ((kc ^ ((ra >> 1) & 3)) << 4);
        int rb = wc * 64 + m * 16 + rl;
        boff[m] = rb * 64 + ((kc ^ ((rb >> 1) & 3)) << 4);
    }

    f32x4 acc[4][4];
    #pragma unroll
    for (int m = 0; m < 4; ++m)
        #pragma unroll
        for (int n = 0; n < 4; ++n)
            acc[m][n] = (f32x4){0.f, 0.f, 0.f, 0.f};

    char* Lb = (char*)lds;
    for (int k0 = 0; k0 < K; k0 += 32) {
        __syncthreads();
        #pragma unroll
        for (int c = 0; c < 2; ++c) {
            __builtin_amdgcn_global_load_lds((const AS1 unsigned*)(Ahi + gA[c] + k0),
                (AS3 unsigned*)(Lb + 0 * 8192 + c * 4096 + w * 1024), 16, 0, 0);
            __builtin_amdgcn_global_load_lds((const AS1 unsigned*)(Alo + gA[c] + k0),
                (AS3 unsigned*)(Lb + 1 * 8192 + c * 4096 + w * 1024), 16, 0, 0);
            __builtin_amdgcn_global_load_lds((const AS1 unsigned*)(Bhi + gB[c] + k0),
                (AS3 unsigned*)(Lb + 2 * 8192 + c * 4096 + w * 1024), 16, 0, 0);
            __builtin_amdgcn_global_load_lds((const AS1 unsigned*)(Blo + gB[c] + k0),
                (AS3 unsigned*)(Lb + 3 * 8192 + c * 4096 + w * 1024), 16, 0, 0);
        }
        __syncthreads();
        short8 ah[4], al[4];
        #pragma unroll
        for (int m = 0; m < 4; ++m) {
            ah[m] = *(const short8*)(Lb + aoff[m]);
            al[m] = *(const short8*)(Lb + 8192 + aoff[m]);
        }
        #pragma unroll
        for (int n = 0; n < 4; ++n) {
            short8 bh = *(const short8*)(Lb + 16384 + boff[n]);
            short8 bl = *(const short8*)(Lb + 24576 + boff[n]);
            #pragma unroll
            for (int m = 0; m < 4; ++m) {
                acc[m][n] = __builtin_amdgcn_mfma_f32_16x16x32_bf16(ah[m], bh, acc[m][n], 0, 0, 0);
                acc[m][n] = __builtin_amdgcn_mfma_f32_16x16x32_bf16(ah[m], bl, acc[m][n], 0, 0, 0);
                acc[m][n] = __builtin_amdgcn_mfma_f32_16x16x32_bf16(al[m], bh, acc[m][n], 0, 0, 0);
            }
        }
    }
    // epilogue: C/D layout col = lane&15, row = (lane>>4)*4 + j
    #pragma unroll
    for (int m = 0; m < 4; ++m) {
        int row0 = bm + wr * 64 + m * 16 + kc * 4;
        #pragma unroll
        for (int n = 0; n < 4; ++n) {
            int col = bn + wc * 64 + n * 16 + rl;
            #pragma unroll
            for (int j = 0; j < 4; ++j)
                C[(size_t)(row0 + j) * ldc + col] = acc[m][n][j];
        }
    }
}

// ---------------- fused causal attention (online softmax, fp32 math) ---------
// qkv: [4096, 3072]; out: bf16 hi/lo [4096, 1024]
__global__ __launch_bounds__(256) void attn_kernel(
    const float* __restrict__ qkv,
    ushort* __restrict__ Ohi, ushort* __restrict__ Olo) {
    int bh = blockIdx.x;           // 0..63
    int b = bh >> 4, h = bh & 15;
    int i0 = blockIdx.y * 4;
    int w = threadIdx.x >> 6, lane = threadIdx.x & 63;
    int i = i0 + w;                // this wave's query row
    __shared__ float kt[64][68];
    __shared__ float vt[64][68];
    __shared__ float qs[4][64];
    __shared__ float ps[4][64];
    size_t base = ((size_t)b * SEQ) * 3072 + (size_t)h * 64;
    float qv = qkv[base + (size_t)i * 3072 + lane] * 0.125f;  // 64^-0.5
    qs[w][lane] = qv;
    float m = -INFINITY, l = 0.f, o = 0.f;
    int ntiles = (i0 + 3) / 64 + 1;
    for (int jt = 0; jt < ntiles; ++jt) {
        __syncthreads();
        for (int t = threadIdx.x; t < 1024; t += 256) {
            int jr = t >> 4;
            int c = (t & 15) * 4;
            size_t gg = base + (size_t)(jt * 64 + jr) * 3072 + c;
            *(float4*)&kt[jr][c] = *(const float4*)(qkv + gg + 1024);
            *(float4*)&vt[jr][c] = *(const float4*)(qkv + gg + 2048);
        }
        __syncthreads();
        if ((i >> 6) >= jt) {
            int j = jt * 64 + lane;
            float s = 0.f;
            #pragma unroll
            for (int dd = 0; dd < 16; ++dd) {
                float4 q4 = *(const float4*)&qs[w][dd * 4];
                float4 k4 = *(const float4*)&kt[lane][dd * 4];
                s = fmaf(q4.x, k4.x, s);
                s = fmaf(q4.y, k4.y, s);
                s = fmaf(q4.z, k4.z, s);
                s = fmaf(q4.w, k4.w, s);
            }
            bool valid = (j <= i);
            s = valid ? s : -INFINITY;
            float tmax = wave_max(s);
            float mnew = fmaxf(m, tmax);
            float p = valid ? __expf(s - mnew) : 0.f;
            float corr = __expf(m - mnew);
            float psum = wave_sum(p);
            l = l * corr + psum;
            m = mnew;
            ps[w][lane] = p;
            o *= corr;
            #pragma unroll
            for (int j4 = 0; j4 < 16; ++j4) {
                float4 p4 = *(const float4*)&ps[w][j4 * 4];
                o = fmaf(p4.x, vt[j4 * 4 + 0][lane], o);
                o = fmaf(p4.y, vt[j4 * 4 + 1][lane], o);
                o = fmaf(p4.z, vt[j4 * 4 + 2][lane], o);
                o = fmaf(p4.w, vt[j4 * 4 + 3][lane], o);
            }
        }
    }
    float res = o / l;
    size_t oi = ((size_t)b * SEQ + i) * 1024 + h * 64 + lane;
    ushort hh, ll;
    split2(res, hh, ll);
    Ohi[oi] = hh;
    Olo[oi] = ll;
}

// ---------------- GEGLU: hh[r,c] = a * gelu_exact(gate), in-place ------------
__global__ __launch_bounds__(256) void geglu_kernel(float* __restrict__ hh) {
    size_t idx = (size_t)blockIdx.x * 256 + threadIdx.x;
    size_t r = idx >> 10;
    int c = (int)(idx & 1023) * 4;
    float* arow = hh + r * 8192;
    float4 a = *(const float4*)(arow + c);
    float4 g = *(const float4*)(arow + 4096 + c);
    float4 o;
    o.x = a.x * 0.5f * g.x * (1.f + erff(g.x * 0.70710678118654752f));
    o.y = a.y * 0.5f * g.y * (1.f + erff(g.y * 0.70710678118654752f));
    o.z = a.z * 0.5f * g.z * (1.f + erff(g.z * 0.70710678118654752f));
    o.w = a.w * 0.5f * g.w * (1.f + erff(g.w * 0.70710678118654752f));
    *(float4*)(arow + c) = o;
}

// ---------------- residual add: X += C ---------------------------------------
__global__ __launch_bounds__(256) void add_kernel(
    float* __restrict__ X, const float* __restrict__ Cc) {
    size_t idx = ((size_t)blockIdx.x * 256 + threadIdx.x) * 4;
    float4 x = *(const float4*)(X + idx);
    float4 c = *(const float4*)(Cc + idx);
    x.x += c.x; x.y += c.y; x.z += c.z; x.w += c.w;
    *(float4*)(X + idx) = x;
}

extern "C" void kernel_launch(void* const* d_in, const int* in_sizes, int n_in,
                              void* d_out, int out_size, void* d_ws, size_t ws_size,
                              hipStream_t stream) {
    const float* x_in    = (const float*)d_in[0];
    const float* qkv_w   = (const float*)d_in[1];
    const float* out_w   = (const float*)d_in[2];
    const float* ff_w1   = (const float*)d_in[3];
    const float* ff_w2   = (const float*)d_in[4];
    const float* attn_g  = (const float*)d_in[5];
    const float* outln_g = (const float*)d_in[6];
    const float* ffn_g   = (const float*)d_in[7];
    const float* ffln_g  = (const float*)d_in[8];
    const float* nin_g   = (const float*)d_in[9];
    const float* nout_g  = (const float*)d_in[10];
    float* out = (float*)d_out;

    const size_t T = NTOK;
    float*  X   = (float*)d_ws;           // [4096,1024] residual stream (fp32)
    float*  Cb  = X + T * 1024;           // [4096,1024] proj/ff2 output (fp32)
    float*  BIG = Cb + T * 1024;          // [4096,8192] qkv / ff inner (fp32)
    ushort* Ahi = (ushort*)(BIG + T * 8192);  // [4096,1024] bf16 hi
    ushort* Alo = Ahi + T * 1024;             // [4096,1024] bf16 lo
    ushort* Ghi = Alo + T * 1024;             // [4096,4096] bf16 hi
    ushort* Glo = Ghi + T * 4096;             // [4096,4096] bf16 lo
    ushort* Whi = Glo + T * 4096;             // per-layer transposed weights hi
    const size_t WTOT = (size_t)3072 * 1024 + 1024 * 1024 + 8192 * 1024 + 1024 * 4096; // 16777216
    ushort* Wlo = Whi + WTOT;

    ushort* Wq_h = Whi;                    ushort* Wq_l = Wlo;
    ushort* Wo_h = Whi + 3145728;          ushort* Wo_l = Wlo + 3145728;
    ushort* W1_h = Whi + 4194304;          ushort* W1_l = Wlo + 4194304;
    ushort* W2_h = Whi + 12582912;         ushort* W2_l = Wlo + 12582912;

    dim3 blk(256);
    // x = LN(x, norm_in_g) -> X (fp32 residual stream)
    ln_kernel<1><<<NTOK, blk, 0, stream>>>(x_in, 1024, X, 1024, nin_g, nullptr);

    for (int l = 0; l < 6; ++l) {
        // weight transpose+split for this layer
        tsplit_kernel<<<dim3(96, 32), blk, 0, stream>>>(qkv_w + (size_t)l * 1024 * 3072, Wq_h, Wq_l, 1024, 3072);
        tsplit_kernel<<<dim3(32, 32), blk, 0, stream>>>(out_w + (size_t)l * 1024 * 1024, Wo_h, Wo_l, 1024, 1024);
        tsplit_kernel<<<dim3(256, 32), blk, 0, stream>>>(ff_w1 + (size_t)l * 1024 * 8192, W1_h, W1_l, 1024, 8192);
        tsplit_kernel<<<dim3(32, 128), blk, 0, stream>>>(ff_w2 + (size_t)l * 4096 * 1024, W2_h, W2_l, 4096, 1024);

        // --- attention block ---
        ln_split_kernel<1><<<NTOK, blk, 0, stream>>>(X, 1024, Ahi, Alo, attn_g + l * 1024);
        mgemm_kernel<<<dim3(32, 24), blk, 0, stream>>>(Ahi, Alo, Wq_h, Wq_l, BIG, 3072, 1024);
        attn_kernel<<<dim3(64, 256), blk, 0, stream>>>(BIG, Ahi, Alo);
        mgemm_kernel<<<dim3(32, 8), blk, 0, stream>>>(Ahi, Alo, Wo_h, Wo_l, Cb, 1024, 1024);
        ln_kernel<1><<<NTOK, blk, 0, stream>>>(Cb, 1024, X, 1024, outln_g + l * 1024, X);

        // --- GEGLU feedforward block ---
        ln_split_kernel<1><<<NTOK, blk, 0, stream>>>(X, 1024, Ahi, Alo, ffn_g + l * 1024);
        mgemm_kernel<<<dim3(32, 64), blk, 0, stream>>>(Ahi, Alo, W1_h, W1_l, BIG, 8192, 1024);
        geglu_kernel<<<16384, blk, 0, stream>>>(BIG);
        ln_split_kernel<4><<<NTOK, blk, 0, stream>>>(BIG, 8192, Ghi, Glo, ffln_g + l * 4096);
        mgemm_kernel<<<dim3(32, 8), blk, 0, stream>>>(Ghi, Glo, W2_h, W2_l, Cb, 1024, 4096);
        add_kernel<<<4096, blk, 0, stream>>>(X, Cb);
    }
    ln_kernel<1><<<NTOK, blk, 0, stream>>>(X, 1024, out, 1024, nout_g, nullptr);
}